// Round 1
// baseline (226.448 us; speedup 1.0000x reference)
//
#include <hip/hip_runtime.h>
#include <cstdint>
#include <cstddef>

// Problem dims (fixed by reference setup)
#define B_  4
#define T_  4096
#define V_  1024
#define NDJ 5            // band tiles of 128 along s-t: covers s-t in [1, 639]
#define NTI (T_/128)     // 32 t-tiles
#define NVB (V_/128)     // 8 v-blocks

typedef __attribute__((ext_vector_type(4))) float  f32x4;
typedef __attribute__((ext_vector_type(8))) __bf16 bf16x8;

typedef const __attribute__((address_space(1))) void* gas_ptr;
typedef __attribute__((address_space(3)))       void* las_ptr;

__device__ __forceinline__ void gload16(const void* g, void* l) {
  // async global->LDS, 16B per lane; LDS dest = wave-uniform base + lane*16
  __builtin_amdgcn_global_load_lds((gas_ptr)g, (las_ptr)l, 16, 0, 0);
}

// f32 -> bf16 round-to-nearest-even, pure bit ops
__device__ __forceinline__ unsigned short f2bf(float f) {
  unsigned int u = __float_as_uint(f);
  u += 0x7fffu + ((u >> 16) & 1u);
  return (unsigned short)(u >> 16);
}

// ---------------------------------------------------------------------------
// Prepass: Aq = bf16(x * q_scale*k_scale) [B][T][V]
//          Xb = bf16(x)                   [B][T][V]
//          Xt = bf16(x) transposed        [B][V][T]
// One block transposes a 64(t) x 64(v) tile.
// ---------------------------------------------------------------------------
__global__ __launch_bounds__(256) void prep_kernel(
    const float* __restrict__ x, const float* __restrict__ q_scale,
    const float* __restrict__ k_scale, unsigned short* __restrict__ Aq,
    unsigned short* __restrict__ Xb, unsigned short* __restrict__ Xt)
{
  __shared__ unsigned short tile[64][65];   // +1 pad breaks bank conflicts
  const int b   = blockIdx.y;
  const int tid = threadIdx.x;
  const int ti  = blockIdx.x / (V_/64);
  const int vi  = blockIdx.x % (V_/64);
  const int t0 = ti*64, v0 = vi*64;
  const int cg = tid & 15;     // column group (4 floats)
  const int rr = tid >> 4;     // 0..15
  const int col = cg*4;

  float g[4];
  #pragma unroll
  for (int j = 0; j < 4; ++j) g[j] = q_scale[v0+col+j] * k_scale[v0+col+j];

  #pragma unroll
  for (int rep = 0; rep < 4; ++rep) {
    const int row = rep*16 + rr;                 // t within tile
    const size_t gi = ((size_t)b*T_ + t0+row)*V_ + v0 + col;
    const float4 v = *reinterpret_cast<const float4*>(&x[gi]);
    ushort4 xbv, aqv;
    xbv.x = f2bf(v.x);        xbv.y = f2bf(v.y);
    xbv.z = f2bf(v.z);        xbv.w = f2bf(v.w);
    aqv.x = f2bf(v.x*g[0]);   aqv.y = f2bf(v.y*g[1]);
    aqv.z = f2bf(v.z*g[2]);   aqv.w = f2bf(v.w*g[3]);
    *reinterpret_cast<ushort4*>(&Xb[gi]) = xbv;
    *reinterpret_cast<ushort4*>(&Aq[gi]) = aqv;
    tile[row][col+0] = xbv.x; tile[row][col+1] = xbv.y;
    tile[row][col+2] = xbv.z; tile[row][col+3] = xbv.w;
  }
  __syncthreads();
  #pragma unroll
  for (int rep = 0; rep < 4; ++rep) {
    const int vrow = rep*16 + rr;                // v within tile
    const int tcol = cg*4;                       // t within tile
    ushort4 o;
    o.x = tile[tcol+0][vrow]; o.y = tile[tcol+1][vrow];
    o.z = tile[tcol+2][vrow]; o.w = tile[tcol+3][vrow];
    *reinterpret_cast<ushort4*>(
        &Xt[((size_t)b*V_ + v0+vrow)*T_ + t0 + tcol]) = o;
  }
}

// ---------------------------------------------------------------------------
// Stage a 128-row x 64-col(bf16) tile (128B per row) from row-major global
// into LDS via global_load_lds, with 16B-slot XOR swizzle applied on the
// GLOBAL source (G21: linear LDS dest + inverse-swizzled source).
// LDS[row][slot] = G[row][slot ^ (row&7)]
// ---------------------------------------------------------------------------
__device__ __forceinline__ void stage_tile(const unsigned short* gbase,
                                           int ldg_elems,
                                           unsigned short* lds, int tid)
{
  const int lane = tid & 63;
  const int wave = tid >> 6;
  #pragma unroll
  for (int c = 0; c < 4; ++c) {
    const int obase = c*4096 + wave*1024;        // wave-uniform LDS byte base
    const int o     = obase + lane*16;           // this lane's dest byte
    const int row   = o >> 7;                    // 128B rows
    const int slot  = (o >> 4) & 7;
    const int sslot = slot ^ (row & 7);
    const char* src = reinterpret_cast<const char*>(gbase)
                    + (size_t)row * ((size_t)ldg_elems*2) + sslot*16;
    gload16(src, reinterpret_cast<char*>(lds) + obase);
  }
}

// Swizzled fragment read: 8 contiguous bf16 of (row, 16B k-slot kslot)
__device__ __forceinline__ bf16x8 frag_ld(const unsigned short* lds,
                                          int row, int kslot)
{
  const int off = row*128 + ((kslot ^ (row & 7)) << 4);   // bytes
  return *reinterpret_cast<const bf16x8*>(
      reinterpret_cast<const char*>(lds) + off);
}

// ---------------------------------------------------------------------------
// Pass 1: banded weighted scores.
// Block (b, i, dj): 128x128 tile S[t, s], t in [128i,128i+128),
// s in [128(i+dj), ...). S = Aq_rows · Xb_rowsᵀ over K=V=1024.
// Epilogue: P = S * ((s>t) ? decay^(s-t-1) : 0), stored bf16.
// P layout: [b][i][dj][t_local 128][s_local 128].
// ---------------------------------------------------------------------------
__global__ __launch_bounds__(256) void pass1_scores(
    const unsigned short* __restrict__ Aq, const unsigned short* __restrict__ Xb,
    unsigned short* __restrict__ P, const float* __restrict__ decay_logit)
{
  __shared__ __align__(16) unsigned short As[128*64];
  __shared__ __align__(16) unsigned short Bs[128*64];
  const int tid = threadIdx.x;
  const int dj  = blockIdx.x % NDJ;
  const int i   = (blockIdx.x / NDJ) % NTI;
  const int b   = blockIdx.x / (NDJ*NTI);
  if (i + dj >= NTI) return;                     // band clipped at T
  const int wave = tid >> 6, lane = tid & 63;
  const int wr = wave >> 1, wc = wave & 1;       // 2x2 waves, 64x64 each
  const int lr = lane & 15, kg = lane >> 4;

  f32x4 acc[4][4] = {};

  const unsigned short* Abase = Aq + ((size_t)b*T_ + (size_t)i*128)*V_;
  const unsigned short* Bbase = Xb + ((size_t)b*T_ + (size_t)(i+dj)*128)*V_;

  for (int kt = 0; kt < V_/64; ++kt) {           // 16 K-tiles of 64
    stage_tile(Abase + kt*64, V_, As, tid);
    stage_tile(Bbase + kt*64, V_, Bs, tid);
    __syncthreads();                             // drains vmcnt + barrier
    #pragma unroll
    for (int ks = 0; ks < 2; ++ks) {             // two K=32 MFMA steps
      bf16x8 af[4], bfv[4];
      #pragma unroll
      for (int m = 0; m < 4; ++m) af[m]  = frag_ld(As, wr*64 + m*16 + lr, ks*4 + kg);
      #pragma unroll
      for (int n = 0; n < 4; ++n) bfv[n] = frag_ld(Bs, wc*64 + n*16 + lr, ks*4 + kg);
      #pragma unroll
      for (int m = 0; m < 4; ++m)
        #pragma unroll
        for (int n = 0; n < 4; ++n)
          acc[m][n] = __builtin_amdgcn_mfma_f32_16x16x32_bf16(
              af[m], bfv[n], acc[m][n], 0, 0, 0);
    }
    __syncthreads();                             // reads done before re-stage
  }

  const float dl    = decay_logit[0];
  const float decay = 1.0f / (1.0f + __expf(-dl));
  const float l2d   = __log2f(decay);
  unsigned short* Pb = P + (((size_t)(b*NTI + i)*NDJ + dj) << 14);
  #pragma unroll
  for (int m = 0; m < 4; ++m)
    #pragma unroll
    for (int n = 0; n < 4; ++n)
      #pragma unroll
      for (int r = 0; r < 4; ++r) {
        const int tl = wr*64 + m*16 + kg*4 + r;  // C/D: row = (lane>>4)*4+reg
        const int sl = wc*64 + n*16 + lr;        // C/D: col = lane&15
        const int e  = dj*128 + sl - tl - 1;     // s - t - 1
        const float w = (e >= 0) ? exp2f((float)e * l2d) : 0.0f;
        Pb[tl*128 + sl] = f2bf(acc[m][n][r] * w);
      }
}

// ---------------------------------------------------------------------------
// Pass 2: out[t, v] = out_scale * sum_s P[t,s] * X[s,v].
// Block (b, i, vb): 128x128 output tile; K-loop over dj (5) x half (2), K=64.
// A = P tile rows (t, k=s contiguous); B = Xt rows (v, k=s contiguous).
// ---------------------------------------------------------------------------
__global__ __launch_bounds__(256) void pass2_out(
    const unsigned short* __restrict__ P, const unsigned short* __restrict__ Xt,
    float* __restrict__ out, const float* __restrict__ out_scale)
{
  __shared__ __align__(16) unsigned short As[128*64];
  __shared__ __align__(16) unsigned short Bs[128*64];
  const int tid = threadIdx.x;
  const int vb  = blockIdx.x % NVB;
  const int i   = (blockIdx.x / NVB) % NTI;
  const int b   = blockIdx.x / (NVB*NTI);
  const int wave = tid >> 6, lane = tid & 63;
  const int wr = wave >> 1, wc = wave & 1;
  const int lr = lane & 15, kg = lane >> 4;

  f32x4 acc[4][4] = {};

  for (int kt = 0; kt < 2*NDJ; ++kt) {
    const int dj = kt >> 1, half = kt & 1;
    if (i + dj >= NTI) break;                    // uniform across block
    const unsigned short* Abase =
        P + (((size_t)(b*NTI + i)*NDJ + dj) << 14) + half*64;
    const unsigned short* Bbase =
        Xt + ((size_t)b*V_ + (size_t)vb*128)*T_ + (size_t)(i+dj)*128 + half*64;
    stage_tile(Abase, 128, As, tid);
    stage_tile(Bbase, T_,  Bs, tid);
    __syncthreads();
    #pragma unroll
    for (int ks = 0; ks < 2; ++ks) {
      bf16x8 af[4], bfv[4];
      #pragma unroll
      for (int m = 0; m < 4; ++m) af[m]  = frag_ld(As, wr*64 + m*16 + lr, ks*4 + kg);
      #pragma unroll
      for (int n = 0; n < 4; ++n) bfv[n] = frag_ld(Bs, wc*64 + n*16 + lr, ks*4 + kg);
      #pragma unroll
      for (int m = 0; m < 4; ++m)
        #pragma unroll
        for (int n = 0; n < 4; ++n)
          acc[m][n] = __builtin_amdgcn_mfma_f32_16x16x32_bf16(
              af[m], bfv[n], acc[m][n], 0, 0, 0);
    }
    __syncthreads();
  }

  const float os = out_scale[0];
  float* ob = out + ((size_t)b*T_ + (size_t)i*128)*V_ + (size_t)vb*128;
  #pragma unroll
  for (int m = 0; m < 4; ++m)
    #pragma unroll
    for (int n = 0; n < 4; ++n)
      #pragma unroll
      for (int r = 0; r < 4; ++r) {
        const int tl = wr*64 + m*16 + kg*4 + r;
        const int vl = wc*64 + n*16 + lr;
        ob[(size_t)tl*V_ + vl] = acc[m][n][r] * os;
      }
}

// ---------------------------------------------------------------------------
extern "C" void kernel_launch(void* const* d_in, const int* in_sizes, int n_in,
                              void* d_out, int out_size, void* d_ws, size_t ws_size,
                              hipStream_t stream)
{
  const float* x           = (const float*)d_in[0];
  const float* decay_logit = (const float*)d_in[1];
  const float* out_scale   = (const float*)d_in[2];
  const float* q_scale     = (const float*)d_in[3];
  const float* k_scale     = (const float*)d_in[4];
  float* out = (float*)d_out;

  // ws layout (bf16/ushort elements): Aq | Xb | Xt | P  (~116 MB total)
  const size_t n = (size_t)B_ * T_ * V_;
  unsigned short* Aq = (unsigned short*)d_ws;
  unsigned short* Xb = Aq + n;
  unsigned short* Xt = Xb + n;
  unsigned short* P  = Xt + n;

  prep_kernel<<<dim3((T_/64)*(V_/64), B_), 256, 0, stream>>>(
      x, q_scale, k_scale, Aq, Xb, Xt);
  pass1_scores<<<B_*NTI*NDJ, 256, 0, stream>>>(Aq, Xb, P, decay_logit);
  pass2_out<<<B_*NTI*NVB, 256, 0, stream>>>(P, Xt, out, out_scale);
}

// Round 4
// 214.054 us; speedup vs baseline: 1.0579x; 1.0579x over previous
//
#include <hip/hip_runtime.h>
#include <cstdint>
#include <cstddef>

// Problem dims (fixed by reference setup)
#define B_  4
#define T_  4096
#define V_  1024
#define NDJ 5            // band tiles of 128 along s-t: covers s-t in [1, 639]
#define NTI (T_/128)     // 32 t-tiles
#define NVB (V_/128)     // 8 v-blocks

typedef __attribute__((ext_vector_type(4))) float  f32x4;
typedef __attribute__((ext_vector_type(8))) __bf16 bf16x8;

typedef const __attribute__((address_space(1))) void* gas_ptr;
typedef __attribute__((address_space(3)))       void* las_ptr;

__device__ __forceinline__ void gload16(const void* g, void* l) {
  // async global->LDS, 16B per lane; LDS dest = wave-uniform base + lane*16
  __builtin_amdgcn_global_load_lds((gas_ptr)g, (las_ptr)l, 16, 0, 0);
}

// f32 -> bf16 round-to-nearest-even, pure bit ops
__device__ __forceinline__ unsigned short f2bf(float f) {
  unsigned int u = __float_as_uint(f);
  u += 0x7fffu + ((u >> 16) & 1u);
  return (unsigned short)(u >> 16);
}

// ---------------------------------------------------------------------------
// Prepass: Aq = bf16(x * q_scale*k_scale) [B][T][V]
//          Xb = bf16(x)                   [B][T][V]
//          Xt = bf16(x) transposed        [B][V][T]
// One block transposes a 64(t) x 64(v) tile.
// ---------------------------------------------------------------------------
__global__ __launch_bounds__(256) void prep_kernel(
    const float* __restrict__ x, const float* __restrict__ q_scale,
    const float* __restrict__ k_scale, unsigned short* __restrict__ Aq,
    unsigned short* __restrict__ Xb, unsigned short* __restrict__ Xt)
{
  __shared__ unsigned short tile[64][65];   // +1 pad breaks bank conflicts
  const int b   = blockIdx.y;
  const int tid = threadIdx.x;
  const int ti  = blockIdx.x / (V_/64);
  const int vi  = blockIdx.x % (V_/64);
  const int t0 = ti*64, v0 = vi*64;
  const int cg = tid & 15;     // column group (4 floats)
  const int rr = tid >> 4;     // 0..15
  const int col = cg*4;

  float g[4];
  #pragma unroll
  for (int j = 0; j < 4; ++j) g[j] = q_scale[v0+col+j] * k_scale[v0+col+j];

  #pragma unroll
  for (int rep = 0; rep < 4; ++rep) {
    const int row = rep*16 + rr;                 // t within tile
    const size_t gi = ((size_t)b*T_ + t0+row)*V_ + v0 + col;
    const float4 v = *reinterpret_cast<const float4*>(&x[gi]);
    ushort4 xbv, aqv;
    xbv.x = f2bf(v.x);        xbv.y = f2bf(v.y);
    xbv.z = f2bf(v.z);        xbv.w = f2bf(v.w);
    aqv.x = f2bf(v.x*g[0]);   aqv.y = f2bf(v.y*g[1]);
    aqv.z = f2bf(v.z*g[2]);   aqv.w = f2bf(v.w*g[3]);
    *reinterpret_cast<ushort4*>(&Xb[gi]) = xbv;
    *reinterpret_cast<ushort4*>(&Aq[gi]) = aqv;
    tile[row][col+0] = xbv.x; tile[row][col+1] = xbv.y;
    tile[row][col+2] = xbv.z; tile[row][col+3] = xbv.w;
  }
  __syncthreads();
  #pragma unroll
  for (int rep = 0; rep < 4; ++rep) {
    const int vrow = rep*16 + rr;                // v within tile
    const int tcol = cg*4;                       // t within tile
    ushort4 o;
    o.x = tile[tcol+0][vrow]; o.y = tile[tcol+1][vrow];
    o.z = tile[tcol+2][vrow]; o.w = tile[tcol+3][vrow];
    *reinterpret_cast<ushort4*>(
        &Xt[((size_t)b*V_ + v0+vrow)*T_ + t0 + tcol]) = o;
  }
}

// ---------------------------------------------------------------------------
// Stage a 128-row x 64-col(bf16) tile (128B per row) from row-major global
// into LDS via global_load_lds, with 16B-slot XOR swizzle applied on the
// GLOBAL source (G21: linear LDS dest + inverse-swizzled source).
// LDS[row][slot] = G[row][slot ^ (row&7)]
// ---------------------------------------------------------------------------
__device__ __forceinline__ void stage_tile(const unsigned short* gbase,
                                           int ldg_elems,
                                           unsigned short* lds, int tid)
{
  const int lane = tid & 63;
  const int wave = tid >> 6;
  #pragma unroll
  for (int c = 0; c < 4; ++c) {
    const int obase = c*4096 + wave*1024;        // wave-uniform LDS byte base
    const int o     = obase + lane*16;           // this lane's dest byte
    const int row   = o >> 7;                    // 128B rows
    const int slot  = (o >> 4) & 7;
    const int sslot = slot ^ (row & 7);
    const char* src = reinterpret_cast<const char*>(gbase)
                    + (size_t)row * ((size_t)ldg_elems*2) + sslot*16;
    gload16(src, reinterpret_cast<char*>(lds) + obase);
  }
}

// Swizzled fragment read: 8 contiguous bf16 of (row, 16B k-slot kslot)
__device__ __forceinline__ bf16x8 frag_ld(const unsigned short* lds,
                                          int row, int kslot)
{
  const int off = row*128 + ((kslot ^ (row & 7)) << 4);   // bytes
  return *reinterpret_cast<const bf16x8*>(
      reinterpret_cast<const char*>(lds) + off);
}

// One K=64 compute step: 8 frag loads + 32 MFMA from a staged A/B buffer pair
__device__ __forceinline__ void compute_step(
    const unsigned short* As, const unsigned short* Bs,
    int wr, int wc, int lr, int kg, f32x4 acc[4][4])
{
  #pragma unroll
  for (int ks = 0; ks < 2; ++ks) {               // two K=32 MFMA steps
    bf16x8 af[4], bfv[4];
    #pragma unroll
    for (int m = 0; m < 4; ++m) af[m]  = frag_ld(As, wr*64 + m*16 + lr, ks*4 + kg);
    #pragma unroll
    for (int n = 0; n < 4; ++n) bfv[n] = frag_ld(Bs, wc*64 + n*16 + lr, ks*4 + kg);
    #pragma unroll
    for (int m = 0; m < 4; ++m)
      #pragma unroll
      for (int n = 0; n < 4; ++n)
        acc[m][n] = __builtin_amdgcn_mfma_f32_16x16x32_bf16(
            af[m], bfv[n], acc[m][n], 0, 0, 0);
  }
}

// ---------------------------------------------------------------------------
// Pass 1: banded weighted scores. 2-phase double-buffered K-loop.
// Block (b, i, dj): 128x128 tile S[t, s], t in [128i, ...), s in [128(i+dj), ...).
// S = Aq_rows · Xb_rowsᵀ over K=V=1024.
// Epilogue: P = S * ((s>t) ? decay^(s-t-1) : 0), stored bf16.
// P layout: [b][i][dj][t_local 128][s_local 128].
// ---------------------------------------------------------------------------
__global__ __launch_bounds__(256) void pass1_scores(
    const unsigned short* __restrict__ Aq, const unsigned short* __restrict__ Xb,
    unsigned short* __restrict__ P, const float* __restrict__ decay_logit)
{
  __shared__ __align__(16) unsigned short As[2][128*64];   // 32 KB
  __shared__ __align__(16) unsigned short Bs[2][128*64];   // 32 KB
  const int tid = threadIdx.x;
  // XCD-aware bijective swizzle: nwg = 640, 640 % 8 == 0, cpx = 80.
  const int wg  = (blockIdx.x & 7) * (B_*NTI*NDJ/8) + (blockIdx.x >> 3);
  const int dj  = wg % NDJ;
  const int i   = (wg / NDJ) % NTI;
  const int b   = wg / (NDJ*NTI);
  if (i + dj >= NTI) return;                     // band clipped at T
  const int wave = tid >> 6, lane = tid & 63;
  const int wr = wave >> 1, wc = wave & 1;       // 2x2 waves, 64x64 each
  const int lr = lane & 15, kg = lane >> 4;

  f32x4 acc[4][4] = {};

  const unsigned short* Abase = Aq + ((size_t)b*T_ + (size_t)i*128)*V_;
  const unsigned short* Bbase = Xb + ((size_t)b*T_ + (size_t)(i+dj)*128)*V_;

  const int nt = V_/64;                          // 16 K-steps
  stage_tile(Abase, V_, As[0], tid);
  stage_tile(Bbase, V_, Bs[0], tid);
  __syncthreads();                               // drain vmcnt: buf0 ready
  for (int kt = 0; kt < nt; ++kt) {
    const int cur = kt & 1;
    if (kt + 1 < nt) {                           // prefetch next tile FIRST
      stage_tile(Abase + (kt+1)*64, V_, As[cur^1], tid);
      stage_tile(Bbase + (kt+1)*64, V_, Bs[cur^1], tid);
    }
    compute_step(As[cur], Bs[cur], wr, wc, lr, kg, acc);
    __syncthreads();   // drains vmcnt (next buf staged) + orders reads vs re-stage
  }

  const float dl    = decay_logit[0];
  const float decay = 1.0f / (1.0f + __expf(-dl));
  const float l2d   = __log2f(decay);
  unsigned short* Pb = P + (((size_t)(b*NTI + i)*NDJ + dj) << 14);
  #pragma unroll
  for (int m = 0; m < 4; ++m)
    #pragma unroll
    for (int n = 0; n < 4; ++n)
      #pragma unroll
      for (int r = 0; r < 4; ++r) {
        const int tl = wr*64 + m*16 + kg*4 + r;  // C/D: row = (lane>>4)*4+reg
        const int sl = wc*64 + n*16 + lr;        // C/D: col = lane&15
        const int e  = dj*128 + sl - tl - 1;     // s - t - 1
        const float w = (e >= 0) ? exp2f((float)e * l2d) : 0.0f;
        Pb[tl*128 + sl] = f2bf(acc[m][n][r] * w);
      }
}

// ---------------------------------------------------------------------------
// Pass 2: out[t, v] = out_scale * sum_s P[t,s] * X[s,v]. 2-phase pipeline.
// Block (b, i, vb): 128x128 output tile; K-loop over dj (5) x half (2), K=64.
// A = P tile rows (t, k=s contiguous); B = Xt rows (v, k=s contiguous).
// ---------------------------------------------------------------------------
__global__ __launch_bounds__(256) void pass2_out(
    const unsigned short* __restrict__ P, const unsigned short* __restrict__ Xt,
    float* __restrict__ out, const float* __restrict__ out_scale)
{
  __shared__ __align__(16) unsigned short As[2][128*64];
  __shared__ __align__(16) unsigned short Bs[2][128*64];
  const int tid = threadIdx.x;
  // XCD-aware bijective swizzle: nwg = 1024, cpx = 128.
  const int wg  = (blockIdx.x & 7) * (B_*NTI*NVB/8) + (blockIdx.x >> 3);
  const int vb  = wg % NVB;
  const int i   = (wg / NVB) % NTI;
  const int b   = wg / (NVB*NTI);
  const int wave = tid >> 6, lane = tid & 63;
  const int wr = wave >> 1, wc = wave & 1;
  const int lr = lane & 15, kg = lane >> 4;

  f32x4 acc[4][4] = {};

  // number of valid K=64 steps (uniform): dj in [0, min(NDJ, NTI-i)) x 2 halves
  const int ndj = (NTI - i < NDJ) ? (NTI - i) : NDJ;
  const int nt  = 2*ndj;

  const unsigned short* Pbase =
      P + (((size_t)(b*NTI + i)*NDJ) << 14);
  const unsigned short* Xbase =
      Xt + ((size_t)b*V_ + (size_t)vb*128)*T_ + (size_t)i*128;

  // kt -> (dj = kt>>1, half = kt&1); A row-stride 128, B row-stride T_.
  stage_tile(Pbase, 128, As[0], tid);
  stage_tile(Xbase, T_,  Bs[0], tid);
  __syncthreads();
  for (int kt = 0; kt < nt; ++kt) {
    const int cur = kt & 1;
    if (kt + 1 < nt) {
      const int dj = (kt+1) >> 1, half = (kt+1) & 1;
      stage_tile(Pbase + ((size_t)dj << 14) + half*64, 128, As[cur^1], tid);
      stage_tile(Xbase + (size_t)dj*128 + half*64,     T_,  Bs[cur^1], tid);
    }
    compute_step(As[cur], Bs[cur], wr, wc, lr, kg, acc);
    __syncthreads();
  }

  const float os = out_scale[0];
  float* ob = out + ((size_t)b*T_ + (size_t)i*128)*V_ + (size_t)vb*128;
  #pragma unroll
  for (int m = 0; m < 4; ++m)
    #pragma unroll
    for (int n = 0; n < 4; ++n)
      #pragma unroll
      for (int r = 0; r < 4; ++r) {
        const int tl = wr*64 + m*16 + kg*4 + r;
        const int vl = wc*64 + n*16 + lr;
        ob[(size_t)tl*V_ + vl] = acc[m][n][r] * os;
      }
}

// ---------------------------------------------------------------------------
extern "C" void kernel_launch(void* const* d_in, const int* in_sizes, int n_in,
                              void* d_out, int out_size, void* d_ws, size_t ws_size,
                              hipStream_t stream)
{
  const float* x           = (const float*)d_in[0];
  const float* decay_logit = (const float*)d_in[1];
  const float* out_scale   = (const float*)d_in[2];
  const float* q_scale     = (const float*)d_in[3];
  const float* k_scale     = (const float*)d_in[4];
  float* out = (float*)d_out;

  // ws layout (bf16/ushort elements): Aq | Xb | Xt | P  (~116 MB total)
  const size_t n = (size_t)B_ * T_ * V_;
  unsigned short* Aq = (unsigned short*)d_ws;
  unsigned short* Xb = Aq + n;
  unsigned short* Xt = Xb + n;
  unsigned short* P  = Xt + n;

  prep_kernel<<<dim3((T_/64)*(V_/64), B_), 256, 0, stream>>>(
      x, q_scale, k_scale, Aq, Xb, Xt);
  pass1_scores<<<B_*NTI*NDJ, 256, 0, stream>>>(Aq, Xb, P, decay_logit);
  pass2_out<<<B_*NTI*NVB, 256, 0, stream>>>(P, Xt, out, out_scale);
}

// Round 5
// 183.181 us; speedup vs baseline: 1.2362x; 1.1685x over previous
//
#include <hip/hip_runtime.h>
#include <cstdint>
#include <cstddef>

// Problem dims (fixed by reference setup)
#define B_  4
#define T_  4096
#define V_  1024
#define NI  16           // 256-row t-tiles per batch
#define NDJ 4            // 128-wide s-tiles per t-tile; covers s-t band (tail <= decay^256 ~ 4e-6)
#define NVB 4            // 256-wide v-tiles

typedef __attribute__((ext_vector_type(4))) float  f32x4;
typedef __attribute__((ext_vector_type(8))) __bf16 bf16x8;

typedef const __attribute__((address_space(1))) void* gas_ptr;
typedef __attribute__((address_space(3)))       void* las_ptr;

__device__ __forceinline__ void gload16(const void* g, void* l) {
  // async global->LDS, 16B per lane; LDS dest = wave-uniform base + lane*16
  __builtin_amdgcn_global_load_lds((gas_ptr)g, (las_ptr)l, 16, 0, 0);
}

#define VMWAIT(N) asm volatile("s_waitcnt vmcnt(" #N ")" ::: "memory")
#define BARRIER() asm volatile("s_barrier" ::: "memory")

// f32 -> bf16 round-to-nearest-even, pure bit ops
__device__ __forceinline__ unsigned short f2bf(float f) {
  unsigned int u = __float_as_uint(f);
  u += 0x7fffu + ((u >> 16) & 1u);
  return (unsigned short)(u >> 16);
}

// ---------------------------------------------------------------------------
// Prepass: Aq = bf16(x * q_scale*k_scale) [B][T][V]
//          Xb = bf16(x)                   [B][T][V]
//          Xt = bf16(x) transposed        [B][V][T]
// ---------------------------------------------------------------------------
__global__ __launch_bounds__(256) void prep_kernel(
    const float* __restrict__ x, const float* __restrict__ q_scale,
    const float* __restrict__ k_scale, unsigned short* __restrict__ Aq,
    unsigned short* __restrict__ Xb, unsigned short* __restrict__ Xt)
{
  __shared__ unsigned short tile[64][65];   // +1 pad breaks bank conflicts
  const int b   = blockIdx.y;
  const int tid = threadIdx.x;
  const int ti  = blockIdx.x / (V_/64);
  const int vi  = blockIdx.x % (V_/64);
  const int t0 = ti*64, v0 = vi*64;
  const int cg = tid & 15;     // column group (4 floats)
  const int rr = tid >> 4;     // 0..15
  const int col = cg*4;

  float g[4];
  #pragma unroll
  for (int j = 0; j < 4; ++j) g[j] = q_scale[v0+col+j] * k_scale[v0+col+j];

  #pragma unroll
  for (int rep = 0; rep < 4; ++rep) {
    const int row = rep*16 + rr;                 // t within tile
    const size_t gi = ((size_t)b*T_ + t0+row)*V_ + v0 + col;
    const float4 v = *reinterpret_cast<const float4*>(&x[gi]);
    ushort4 xbv, aqv;
    xbv.x = f2bf(v.x);        xbv.y = f2bf(v.y);
    xbv.z = f2bf(v.z);        xbv.w = f2bf(v.w);
    aqv.x = f2bf(v.x*g[0]);   aqv.y = f2bf(v.y*g[1]);
    aqv.z = f2bf(v.z*g[2]);   aqv.w = f2bf(v.w*g[3]);
    *reinterpret_cast<ushort4*>(&Xb[gi]) = xbv;
    *reinterpret_cast<ushort4*>(&Aq[gi]) = aqv;
    tile[row][col+0] = xbv.x; tile[row][col+1] = xbv.y;
    tile[row][col+2] = xbv.z; tile[row][col+3] = xbv.w;
  }
  __syncthreads();
  #pragma unroll
  for (int rep = 0; rep < 4; ++rep) {
    const int vrow = rep*16 + rr;                // v within tile
    const int tcol = cg*4;                       // t within tile
    ushort4 o;
    o.x = tile[tcol+0][vrow]; o.y = tile[tcol+1][vrow];
    o.z = tile[tcol+2][vrow]; o.w = tile[tcol+3][vrow];
    *reinterpret_cast<ushort4*>(
        &Xt[((size_t)b*V_ + v0+vrow)*T_ + t0 + tcol]) = o;
  }
}

// ---------------------------------------------------------------------------
// Stage ROWS x 64(bf16) tile (128B/row) via global_load_lds with 16B-slot
// XOR swizzle applied on the GLOBAL source (G21): LDS[row][slot] = G[row][slot^ (row&7)].
// 512-thread block: one c-round covers 64 rows (8 waves x 1KB).
// ---------------------------------------------------------------------------
template<int ROWS>
__device__ __forceinline__ void stage_t(const unsigned short* gbase, int ldg_elems,
                                        unsigned short* lds, int tid)
{
  const int lane = tid & 63;
  const int wave = tid >> 6;
  #pragma unroll
  for (int c = 0; c < ROWS/64; ++c) {
    const int obase = c*8192 + wave*1024;        // wave-uniform LDS byte base
    const int o     = obase + lane*16;
    const int row   = o >> 7;
    const int slot  = (o >> 4) & 7;
    const int sslot = slot ^ (row & 7);
    const char* src = reinterpret_cast<const char*>(gbase)
                    + (size_t)row * ((size_t)ldg_elems*2) + sslot*16;
    gload16(src, reinterpret_cast<char*>(lds) + obase);
  }
}

// Swizzled fragment read: 8 contiguous bf16 of (row, 16B k-slot)
__device__ __forceinline__ bf16x8 frag_ld(const unsigned short* lds,
                                          int row, int kslot)
{
  const int off = row*128 + ((kslot ^ (row & 7)) << 4);   // bytes
  return *reinterpret_cast<const bf16x8*>(
      reinterpret_cast<const char*>(lds) + off);
}

// ---------------------------------------------------------------------------
// Pass 1: banded weighted scores. 256(t) x 128(s) tile, 8 waves (4M x 2N),
// BK=64 over K=V=1024, double-buffered with counted vmcnt + raw barriers.
// P layout: [b][i][dj][t_local 256][s_local 128] bf16.
// ---------------------------------------------------------------------------
__global__ __launch_bounds__(512, 1) void pass1_scores(
    const unsigned short* __restrict__ Aq, const unsigned short* __restrict__ Xb,
    unsigned short* __restrict__ P, const float* __restrict__ decay_logit)
{
  __shared__ __align__(16) unsigned short As[2][256*64];   // 2 x 32 KB
  __shared__ __align__(16) unsigned short Bs[2][128*64];   // 2 x 16 KB
  const int tid = threadIdx.x;
  // XCD swizzle: grid 256, 32 consecutive wg per XCD
  const int wg = (blockIdx.x & 7) * 32 + (blockIdx.x >> 3);
  const int dj = wg & 3;
  const int i  = (wg >> 2) & 15;
  const int b  = wg >> 6;
  const int s0 = i*256 + dj*128;                 // s-tile start (within batch)
  if (s0 + 128 > T_) return;                     // clipped (uniform exit, pre-barrier)
  const int wave = tid >> 6, lane = tid & 63;
  const int wr = wave >> 1, wc = wave & 1;       // 4M x 2N waves; wave tile 64x64
  const int lr = lane & 15, kg = lane >> 4;

  f32x4 acc[4][4] = {};

  const unsigned short* Abase = Aq + ((size_t)b*T_ + (size_t)i*256)*V_;
  const unsigned short* Bbase = Xb + ((size_t)b*T_ + (size_t)s0)*V_;

  const int nt = V_/64;                          // 16 K-steps
  stage_t<256>(Abase, V_, As[0], tid);           // 4 loads/wave
  stage_t<128>(Bbase, V_, Bs[0], tid);           // 2 loads/wave  -> 6 in flight
  for (int kt = 0; kt < nt; ++kt) {
    const int cur = kt & 1;
    if (kt + 1 < nt) {
      stage_t<256>(Abase + (kt+1)*64, V_, As[cur^1], tid);
      stage_t<128>(Bbase + (kt+1)*64, V_, Bs[cur^1], tid);
      VMWAIT(6);                                 // wait tile-kt loads; kt+1's stay in flight
    } else {
      VMWAIT(0);
    }
    BARRIER();                                   // tile kt resident block-wide
    #pragma unroll
    for (int ks = 0; ks < 2; ++ks) {
      bf16x8 af[4], bfv[4];
      #pragma unroll
      for (int m = 0; m < 4; ++m) af[m]  = frag_ld(As[cur], wr*64 + m*16 + lr, ks*4 + kg);
      #pragma unroll
      for (int n = 0; n < 4; ++n) bfv[n] = frag_ld(Bs[cur], wc*64 + n*16 + lr, ks*4 + kg);
      #pragma unroll
      for (int m = 0; m < 4; ++m)
        #pragma unroll
        for (int n = 0; n < 4; ++n)
          acc[m][n] = __builtin_amdgcn_mfma_f32_16x16x32_bf16(
              af[m], bfv[n], acc[m][n], 0, 0, 0);
    }
    BARRIER();                                   // all reads done before re-stage
  }

  const float dl    = decay_logit[0];
  const float decay = 1.0f / (1.0f + __expf(-dl));
  const float l2d   = __log2f(decay);
  unsigned short* Pb = P + (((size_t)(b*NI + i)*NDJ + dj) * (256*128));
  #pragma unroll
  for (int m = 0; m < 4; ++m)
    #pragma unroll
    for (int n = 0; n < 4; ++n)
      #pragma unroll
      for (int r = 0; r < 4; ++r) {
        const int tl = wr*64 + m*16 + kg*4 + r;  // C/D: row = (lane>>4)*4+reg, 0..255
        const int sl = wc*64 + n*16 + lr;        // C/D: col = lane&15, 0..127
        const int e  = dj*128 + sl - tl - 1;     // s - t - 1
        const float w = (e >= 0) ? exp2f((float)e * l2d) : 0.0f;
        Pb[tl*128 + sl] = f2bf(acc[m][n][r] * w);
      }
}

// ---------------------------------------------------------------------------
// Pass 2: out[t,v] = out_scale * sum_s P[t,s] * X[s,v]. 256(t) x 256(v) tile,
// 8 waves (2M x 4N), K = NDJ*128 (<=512), same pipeline discipline.
// ---------------------------------------------------------------------------
__global__ __launch_bounds__(512, 1) void pass2_out(
    const unsigned short* __restrict__ P, const unsigned short* __restrict__ Xt,
    float* __restrict__ out, const float* __restrict__ out_scale)
{
  __shared__ __align__(16) unsigned short As[2][256*64];   // 2 x 32 KB
  __shared__ __align__(16) unsigned short Bs[2][256*64];   // 2 x 32 KB
  const int tid = threadIdx.x;
  const int wg = (blockIdx.x & 7) * 32 + (blockIdx.x >> 3);
  const int vb = wg & 3;
  const int i  = (wg >> 2) & 15;
  const int b  = wg >> 6;
  const int wave = tid >> 6, lane = tid & 63;
  const int wr = wave >> 2, wc = wave & 3;       // 2M x 4N waves; wave tile 128x64
  const int lr = lane & 15, kg = lane >> 4;

  f32x4 acc[8][4] = {};

  // valid dj count (s-tile must fit): djmax such that 256i+128dj+128 <= 4096
  const int ndj = (i == NI-1) ? 2 : NDJ;
  const int nt  = 2*ndj;                         // K-steps of 64

  const unsigned short* Pbase = P + (((size_t)(b*NI + i)*NDJ) * (256*128));
  const unsigned short* Xbase =
      Xt + ((size_t)b*V_ + (size_t)vb*256)*T_ + (size_t)i*256;

  // kt -> (dj = kt>>1, half = kt&1). A row-stride 128, B row-stride T_.
  stage_t<256>(Pbase, 128, As[0], tid);          // 4 loads/wave
  stage_t<256>(Xbase, T_,  Bs[0], tid);          // 4 loads/wave -> 8 in flight
  for (int kt = 0; kt < nt; ++kt) {
    const int cur = kt & 1;
    if (kt + 1 < nt) {
      const int dj = (kt+1) >> 1, half = (kt+1) & 1;
      stage_t<256>(Pbase + (size_t)dj*(256*128) + half*64, 128, As[cur^1], tid);
      stage_t<256>(Xbase + (size_t)dj*128 + half*64,       T_,  Bs[cur^1], tid);
      VMWAIT(8);
    } else {
      VMWAIT(0);
    }
    BARRIER();
    #pragma unroll
    for (int ks = 0; ks < 2; ++ks) {
      bf16x8 af[8], bfv[4];
      #pragma unroll
      for (int m = 0; m < 8; ++m) af[m]  = frag_ld(As[cur], wr*128 + m*16 + lr, ks*4 + kg);
      #pragma unroll
      for (int n = 0; n < 4; ++n) bfv[n] = frag_ld(Bs[cur], wc*64 + n*16 + lr, ks*4 + kg);
      #pragma unroll
      for (int m = 0; m < 8; ++m)
        #pragma unroll
        for (int n = 0; n < 4; ++n)
          acc[m][n] = __builtin_amdgcn_mfma_f32_16x16x32_bf16(
              af[m], bfv[n], acc[m][n], 0, 0, 0);
    }
    BARRIER();
  }

  const float os = out_scale[0];
  float* ob = out + ((size_t)b*T_ + (size_t)i*256)*V_ + (size_t)vb*256;
  #pragma unroll
  for (int m = 0; m < 8; ++m)
    #pragma unroll
    for (int n = 0; n < 4; ++n)
      #pragma unroll
      for (int r = 0; r < 4; ++r) {
        const int tl = wr*128 + m*16 + kg*4 + r;
        const int vl = wc*64  + n*16 + lr;
        ob[(size_t)tl*V_ + vl] = acc[m][n][r] * os;
      }
}

// ---------------------------------------------------------------------------
extern "C" void kernel_launch(void* const* d_in, const int* in_sizes, int n_in,
                              void* d_out, int out_size, void* d_ws, size_t ws_size,
                              hipStream_t stream)
{
  const float* x           = (const float*)d_in[0];
  const float* decay_logit = (const float*)d_in[1];
  const float* out_scale   = (const float*)d_in[2];
  const float* q_scale     = (const float*)d_in[3];
  const float* k_scale     = (const float*)d_in[4];
  float* out = (float*)d_out;

  // ws layout (ushort elems): Aq | Xb | Xt | P  (~117 MB)
  const size_t n = (size_t)B_ * T_ * V_;
  unsigned short* Aq = (unsigned short*)d_ws;
  unsigned short* Xb = Aq + n;
  unsigned short* Xt = Xb + n;
  unsigned short* P  = Xt + n;   // B_*NI*NDJ*256*128 = 8.4M elems

  prep_kernel<<<dim3((T_/64)*(V_/64), B_), 256, 0, stream>>>(
      x, q_scale, k_scale, Aq, Xb, Xt);
  pass1_scores<<<B_*NI*NDJ, 512, 0, stream>>>(Aq, Xb, P, decay_logit);
  pass2_out<<<B_*NI*NVB, 512, 0, stream>>>(P, Xt, out, out_scale);
}